// Round 6
// baseline (415.502 us; speedup 1.0000x reference)
//
#include <hip/hip_runtime.h>

#define N_NODES 100000
#define N_EDGES 1600000
#define NTILES (N_NODES / 16)            // 6250 exactly (100000 = 16*6250)

#define BKT_SHIFT 8
#define BKT_NODES 256
#define NBK ((N_NODES + BKT_NODES - 1) / BKT_NODES)      // 391 buckets
#define CHUNK 2048
#define NCHUNKS ((N_EDGES + CHUNK - 1) / CHUNK)          // 782 chunks
#define BCAP 6144                                        // LDS cap per bucket (avg 4096, ~32 sigma)

typedef _Float16 half8 __attribute__((ext_vector_type(8)));
typedef float floatx4 __attribute__((ext_vector_type(4)));

// ---------------- bucket-level histogram (391 bins) ----------------
__global__ __launch_bounds__(512) void bhist_kernel(const int* __restrict__ dst,
                                                    int* __restrict__ bhist) {
    __shared__ int h[NBK];
    for (int i = threadIdx.x; i < NBK; i += 512) h[i] = 0;
    __syncthreads();
    int stride = gridDim.x * 512;
    for (int e = blockIdx.x * 512 + threadIdx.x; e < N_EDGES; e += stride)
        atomicAdd(&h[dst[e] >> BKT_SHIFT], 1);
    __syncthreads();
    for (int i = threadIdx.x; i < NBK; i += 512) {
        int v = h[i];
        if (v) atomicAdd(&bhist[i], v);
    }
}

// ---------------- single-block scan of bucket histogram ----------------
__global__ __launch_bounds__(512) void scan_bhist_kernel(const int* __restrict__ bhist,
                                                         int* __restrict__ bbase,
                                                         int* __restrict__ bcursor) {
    __shared__ int s[512];
    int t = threadIdx.x;
    int v = (t < NBK) ? bhist[t] : 0;
    s[t] = v;
    __syncthreads();
    for (int off = 1; off < 512; off <<= 1) {
        int u = (t >= off) ? s[t - off] : 0;
        __syncthreads();
        s[t] += u;
        __syncthreads();
    }
    if (t < NBK) {
        int excl = s[t] - v;
        bbase[t] = excl;
        bcursor[t] = excl;
    }
    if (t == 0) bbase[NBK] = N_EDGES;
}

// ---------------- phase A: bin edges by 256-node bucket, coalesced runs ----------------
// csr_tmp entry packed: (dst & 255) << 24 | src   (src < 2^17, dloc < 2^8)
__global__ __launch_bounds__(512) void binA_kernel(const int* __restrict__ src,
                                                   const int* __restrict__ dst,
                                                   int* __restrict__ bcursor,
                                                   int* __restrict__ csr_tmp) {
    __shared__ int staged[CHUNK];    // 8 KB
    __shared__ int delta[CHUNK];     // 8 KB
    __shared__ int hist[NBK];
    __shared__ int lcur[NBK];
    __shared__ int gdel[NBK];
    __shared__ int scan_s[512];
    int t = threadIdx.x;
    int e0 = blockIdx.x * CHUNK;
    int n = N_EDGES - e0; if (n > CHUNK) n = CHUNK;

    for (int i = t; i < NBK; i += 512) hist[i] = 0;
    __syncthreads();
    for (int i = t; i < n; i += 512) atomicAdd(&hist[dst[e0 + i] >> BKT_SHIFT], 1);
    __syncthreads();
    int v = (t < NBK) ? hist[t] : 0;
    scan_s[t] = v;
    __syncthreads();
    for (int off = 1; off < 512; off <<= 1) {
        int u = (t >= off) ? scan_s[t - off] : 0;
        __syncthreads();
        scan_s[t] += u;
        __syncthreads();
    }
    if (t < NBK) {
        int excl = scan_s[t] - v;
        lcur[t] = excl;
        int g = atomicAdd(&bcursor[t], v);  // reserve contiguous run in bucket region
        gdel[t] = g - excl;
    }
    __syncthreads();
    for (int i = t; i < n; i += 512) {
        int s = src[e0 + i];
        int d = dst[e0 + i];
        int bkt = d >> BKT_SHIFT;
        int slot = atomicAdd(&lcur[bkt], 1);
        staged[slot] = ((d & 255) << 24) | s;
        delta[slot] = gdel[bkt];
    }
    __syncthreads();
    for (int p = t; p < n; p += 512) csr_tmp[delta[p] + p] = staged[p];
}

// ---------------- phase B: per-bucket hist/scan/offs/dinv + CSR ordering (512 thr) ----------------
__global__ __launch_bounds__(512) void binB_kernel(const int* __restrict__ bbase,
                                                   const int* __restrict__ csr_tmp,
                                                   int* __restrict__ offs,
                                                   float* __restrict__ dinv,
                                                   int* __restrict__ csr) {
    __shared__ int src_s[BCAP];            // 24 KB
    __shared__ unsigned char dloc[BCAP];   // 6 KB
    __shared__ int out_s[BCAP];            // 24 KB
    __shared__ int lcnt[BKT_NODES];
    __shared__ int ss[512];
    __shared__ int lcur[BKT_NODES];
    int t = threadIdx.x;
    int node0 = blockIdx.x * BKT_NODES;
    int base = bbase[blockIdx.x];
    int cnt = bbase[blockIdx.x + 1] - base;
    if (t < BKT_NODES) lcnt[t] = 0;
    __syncthreads();
    bool fits = (cnt <= BCAP);
    if (fits) {
        for (int i = t; i < cnt; i += 512) {
            int e = csr_tmp[base + i];
            int dl = (unsigned int)e >> 24;
            src_s[i] = e & 0x00FFFFFF;
            dloc[i] = (unsigned char)dl;
            atomicAdd(&lcnt[dl], 1);
        }
    } else {
        for (int i = t; i < cnt; i += 512)
            atomicAdd(&lcnt[(unsigned int)csr_tmp[base + i] >> 24], 1);
    }
    __syncthreads();
    int v = (t < BKT_NODES) ? lcnt[t] : 0;
    ss[t] = v;
    __syncthreads();
    for (int off = 1; off < 512; off <<= 1) {
        int u = (t >= off) ? ss[t - off] : 0;
        __syncthreads();
        ss[t] += u;
        __syncthreads();
    }
    int excl = ss[t] - v;
    int node = node0 + t;
    if (t < BKT_NODES) {
        lcur[t] = excl;
        if (node < N_NODES) {
            offs[node] = base + excl;
            dinv[node] = rsqrtf((float)v + 1.0f);
        }
    }
    if (blockIdx.x == NBK - 1 && t == 0) offs[N_NODES] = N_EDGES;
    __syncthreads();
    if (fits) {
        for (int i = t; i < cnt; i += 512) {
            int slot = atomicAdd(&lcur[dloc[i]], 1);
            out_s[slot] = src_s[i];
        }
        __syncthreads();
        for (int i = t; i < cnt; i += 512) csr[base + i] = out_s[i];
    } else {
        for (int i = t; i < cnt; i += 512) {
            int e = csr_tmp[base + i];
            int slot = atomicAdd(&lcur[(unsigned int)e >> 24], 1);
            csr[base + slot] = e & 0x00FFFFFF;
        }
    }
}

// ---------------- prescale: Xs = X * dinv (row-wise) ----------------
__global__ __launch_bounds__(256) void prescale_kernel(const float* __restrict__ X,
                                                       const float* __restrict__ dinv,
                                                       float* __restrict__ Xs) {
    int i = blockIdx.x * 256 + threadIdx.x;  // float4 index
    if (i < N_NODES * 16) {
        float4 v = ((const float4*)X)[i];
        float d = dinv[i >> 4];
        float4 o = make_float4(v.x * d, v.y * d, v.z * d, v.w * d);
        ((float4*)Xs)[i] = o;
    }
}

__device__ inline unsigned int packh(_Float16 a, _Float16 b) {
    unsigned short ua = __builtin_bit_cast(unsigned short, a);
    unsigned short ub = __builtin_bit_cast(unsigned short, b);
    return (unsigned int)ua | ((unsigned int)ub << 16);
}

// ---------------- fused layer: gather (dual-stream, wave-wide) + shuffle-transpose + MFMA ----
// A_n = dinv[n]*(Xs[n] + sum_{s in in(n)} Xs[s]);  out = A @ W + b  [* dinv if prescale_out]
// Per wave: one 16-node tile. Each node gathered by the full wave (proven round-5 loop);
// after the xor-reduce ALL lanes hold the reduced row -> pack f16 hi/lo, 16 shuffles
// redistribute into A-fragment regs of lanes with m==r (no LDS for A).
// MFMA maps (proven): A row = lane&15 (m); B col = lane&15; k = 32c + 8g + j;
// D: col = lane&15 (channel 16t+m), row = 4g+r (node t0+4g+r).
// Products hh+hl+lh (ll ~2^-22, dropped; round-3-proven numerics).
__global__ __launch_bounds__(256) void fused_layer_kernel(
    const float* __restrict__ Xs, const float* __restrict__ dinv,
    const int* __restrict__ offs, const int* __restrict__ csr,
    const float* __restrict__ W, const float* __restrict__ bias,
    float* __restrict__ out, int prescale_out) {
    // W fragments hi/lo, shared per block: [t][c][g][m][j] (lane-contiguous => conflict-free)
    __shared__ __attribute__((aligned(16))) _Float16 Wh[4096];   // 8 KB
    __shared__ __attribute__((aligned(16))) _Float16 Wl[4096];   // 8 KB
    int tid = threadIdx.x;
    for (int u = tid; u < 4096; u += 256) {
        int kk = u >> 6, col = u & 63;
        int tt = col >> 4, mm = col & 15, cc = kk >> 5, gg = (kk >> 3) & 3, jj = kk & 7;
        float w = W[u];
        _Float16 h = (_Float16)w;
        int di = (tt * 2 + cc) * 512 + gg * 128 + mm * 8 + jj;
        Wh[di] = h;
        Wl[di] = (_Float16)(w - (float)h);
    }
    __syncthreads();

    int lane = tid & 63;
    int wv = tid >> 6;
    int g = lane >> 4;       // sub (edge stream) / k-group / D row-group
    int m = lane & 15;       // channel group (gather) / A row / D col
    int tile = blockIdx.x * 4 + wv;
    if (tile >= NTILES) return;
    int t0 = tile * 16;

    const float4* Xv = (const float4*)Xs;

    float bfrag[4];
#pragma unroll
    for (int t = 0; t < 4; t++) bfrag[t] = bias[16 * t + m];

    // persistent A fragments (filled when r == m)
    uint4 ah0q = make_uint4(0, 0, 0, 0), ah1q = make_uint4(0, 0, 0, 0);
    uint4 al0q = make_uint4(0, 0, 0, 0), al1q = make_uint4(0, 0, 0, 0);

    for (int r = 0; r < 16; r++) {
        int node = t0 + r;
        float di = dinv[node];
        int beg = offs[node], end = offs[node + 1];
        float4 acc;
        if (g == 0) {
            acc = Xv[(size_t)node * 16 + m];    // own (pre-scaled) row
        } else {
            acc = make_float4(0.f, 0.f, 0.f, 0.f);
        }
        // dual-stream edge loop (proven: 8 edges/iter/wave, depth-2 per stream)
        int i = beg + g;
        int sA0 = (i      < end) ? csr[i]      : 0;
        int sA1 = (i + 4  < end) ? csr[i + 4]  : 0;
        int sB0 = (i + 8  < end) ? csr[i + 8]  : 0;
        int sB1 = (i + 12 < end) ? csr[i + 12] : 0;
        float4 rA0 = Xv[(size_t)sA0 * 16 + m];
        float4 rA1 = Xv[(size_t)sA1 * 16 + m];
        while (i < end) {
            float4 rB0 = Xv[(size_t)sB0 * 16 + m];
            float4 rB1 = Xv[(size_t)sB1 * 16 + m];
            int sC0 = (i + 16 < end) ? csr[i + 16] : 0;
            int sC1 = (i + 20 < end) ? csr[i + 20] : 0;
            float m1 = (i + 4 < end) ? 1.0f : 0.0f;
            acc.x += rA0.x; acc.y += rA0.y; acc.z += rA0.z; acc.w += rA0.w;
            acc.x = fmaf(rA1.x, m1, acc.x);
            acc.y = fmaf(rA1.y, m1, acc.y);
            acc.z = fmaf(rA1.z, m1, acc.z);
            acc.w = fmaf(rA1.w, m1, acc.w);
            rA0 = rB0; rA1 = rB1;
            sB0 = sC0; sB1 = sC1;
            i += 8;
        }
        // xor-reduce: afterwards ALL lanes hold the full row (channels 4m..4m+3)
        acc.x += __shfl_xor(acc.x, 16, 64); acc.y += __shfl_xor(acc.y, 16, 64);
        acc.z += __shfl_xor(acc.z, 16, 64); acc.w += __shfl_xor(acc.w, 16, 64);
        acc.x += __shfl_xor(acc.x, 32, 64); acc.y += __shfl_xor(acc.y, 32, 64);
        acc.z += __shfl_xor(acc.z, 32, 64); acc.w += __shfl_xor(acc.w, 32, 64);
        acc.x *= di; acc.y *= di; acc.z *= di; acc.w *= di;
        // f16 hi/lo split + pack (2 halfs per uint)
        _Float16 hx = (_Float16)acc.x, hy = (_Float16)acc.y;
        _Float16 hz = (_Float16)acc.z, hw = (_Float16)acc.w;
        _Float16 lx = (_Float16)(acc.x - (float)hx), ly = (_Float16)(acc.y - (float)hy);
        _Float16 lz = (_Float16)(acc.z - (float)hz), lw = (_Float16)(acc.w - (float)hw);
        unsigned int h01 = packh(hx, hy), h23 = packh(hz, hw);
        unsigned int l01 = packh(lx, ly), l23 = packh(lz, lw);
        // shuffle-transpose: lane (g,m) collects (for its row m) channels 32c+8g+j
        // c=0 from lanes 2g,2g+1 ; c=1 from lanes 8+2g,9+2g
        int s0 = 2 * g, s1 = 2 * g + 1, s2 = 8 + 2 * g, s3 = 9 + 2 * g;
        unsigned int a0 = __shfl((int)h01, s0, 64), a1 = __shfl((int)h23, s0, 64);
        unsigned int a2 = __shfl((int)h01, s1, 64), a3 = __shfl((int)h23, s1, 64);
        unsigned int a4 = __shfl((int)h01, s2, 64), a5 = __shfl((int)h23, s2, 64);
        unsigned int a6 = __shfl((int)h01, s3, 64), a7 = __shfl((int)h23, s3, 64);
        unsigned int b0 = __shfl((int)l01, s0, 64), b1 = __shfl((int)l23, s0, 64);
        unsigned int b2 = __shfl((int)l01, s1, 64), b3 = __shfl((int)l23, s1, 64);
        unsigned int b4 = __shfl((int)l01, s2, 64), b5 = __shfl((int)l23, s2, 64);
        unsigned int b6 = __shfl((int)l01, s3, 64), b7 = __shfl((int)l23, s3, 64);
        if (m == r) {
            ah0q = make_uint4(a0, a1, a2, a3);
            ah1q = make_uint4(a4, a5, a6, a7);
            al0q = make_uint4(b0, b1, b2, b3);
            al1q = make_uint4(b4, b5, b6, b7);
        }
    }

    half8 ah0 = __builtin_bit_cast(half8, ah0q);
    half8 ah1 = __builtin_bit_cast(half8, ah1q);
    half8 al0 = __builtin_bit_cast(half8, al0q);
    half8 al1 = __builtin_bit_cast(half8, al1q);

    float dvq[4];
#pragma unroll
    for (int r = 0; r < 4; r++) dvq[r] = dinv[t0 + 4 * g + r];

#pragma unroll
    for (int t = 0; t < 4; t++) {
        half8 bwh0 = *(const half8*)&Wh[(t * 2 + 0) * 512 + g * 128 + m * 8];
        half8 bwl0 = *(const half8*)&Wl[(t * 2 + 0) * 512 + g * 128 + m * 8];
        half8 bwh1 = *(const half8*)&Wh[(t * 2 + 1) * 512 + g * 128 + m * 8];
        half8 bwl1 = *(const half8*)&Wl[(t * 2 + 1) * 512 + g * 128 + m * 8];
        floatx4 d4 = {0.f, 0.f, 0.f, 0.f};
        d4 = __builtin_amdgcn_mfma_f32_16x16x32_f16(ah0, bwh0, d4, 0, 0, 0);
        d4 = __builtin_amdgcn_mfma_f32_16x16x32_f16(ah0, bwl0, d4, 0, 0, 0);
        d4 = __builtin_amdgcn_mfma_f32_16x16x32_f16(al0, bwh0, d4, 0, 0, 0);
        d4 = __builtin_amdgcn_mfma_f32_16x16x32_f16(ah1, bwh1, d4, 0, 0, 0);
        d4 = __builtin_amdgcn_mfma_f32_16x16x32_f16(ah1, bwl1, d4, 0, 0, 0);
        d4 = __builtin_amdgcn_mfma_f32_16x16x32_f16(al1, bwh1, d4, 0, 0, 0);
        float bv = bfrag[t];
#pragma unroll
        for (int r = 0; r < 4; r++) {
            float v = d4[r] + bv;
            if (prescale_out) v *= dvq[r];
            out[(size_t)(t0 + 4 * g + r) * 64 + 16 * t + m] = v;
        }
    }
}

extern "C" void kernel_launch(void* const* d_in, const int* in_sizes, int n_in,
                              void* d_out, int out_size, void* d_ws, size_t ws_size,
                              hipStream_t stream) {
    const float* emb = (const float*)d_in[0];
    const int* edge  = (const int*)d_in[1];
    const float* W1 = (const float*)d_in[2];
    const float* b1 = (const float*)d_in[3];
    const float* W2 = (const float*)d_in[4];
    const float* b2 = (const float*)d_in[5];
    const float* W3 = (const float*)d_in[6];
    const float* b3 = (const float*)d_in[7];
    float* out = (float*)d_out;

    const int* src = edge;
    const int* dst = edge + N_EDGES;

    char* ws = (char*)d_ws;
    size_t off = 0;
    int* bhist = (int*)(ws + off);      off += 2048;
    int* bbase = (int*)(ws + off);      off += 2048;     // NBK+1
    int* bcursor = (int*)(ws + off);    off += 2048;
    int* offs = (int*)(ws + off);       off += 400128;   // N_NODES+1
    float* dinv = (float*)(ws + off);   off += 400128;
    int* csr_tmp = (int*)(ws + off);    off += 6400128;  // packed (dloc<<24)|src
    int* csr = (int*)(ws + off);        off += 6400128;
    float* Xa = (float*)(ws + off);     off += 25600000;
    float* Xb = (float*)(ws + off);     // 25.6 MB

    // ---- CSR build (shared by all 3 layers) ----
    hipMemsetAsync(bhist, 0, NBK * sizeof(int), stream);
    bhist_kernel<<<64, 512, 0, stream>>>(dst, bhist);
    scan_bhist_kernel<<<1, 512, 0, stream>>>(bhist, bbase, bcursor);
    binA_kernel<<<NCHUNKS, 512, 0, stream>>>(src, dst, bcursor, csr_tmp);
    binB_kernel<<<NBK, 512, 0, stream>>>(bbase, csr_tmp, offs, dinv, csr);

    // Xs1 = emb * dinv  -> Xa
    prescale_kernel<<<(N_NODES * 16 + 255) / 256, 256, 0, stream>>>(emb, dinv, Xa);

    const int FBLOCKS = (NTILES + 3) / 4;   // 1563 blocks x 4 waves = 1 tile/wave

    // ---- 3 fused layers (gather + MFMA matmul, no intermediate Agg buffer) ----
    fused_layer_kernel<<<FBLOCKS, 256, 0, stream>>>(Xa, dinv, offs, csr, W1, b1, Xb, 1);
    fused_layer_kernel<<<FBLOCKS, 256, 0, stream>>>(Xb, dinv, offs, csr, W2, b2, Xa, 1);
    fused_layer_kernel<<<FBLOCKS, 256, 0, stream>>>(Xa, dinv, offs, csr, W3, b3, out, 0);
}

// Round 7
// 335.236 us; speedup vs baseline: 1.2394x; 1.2394x over previous
//
#include <hip/hip_runtime.h>

#define N_NODES 100000
#define N_EDGES 1600000
#define NTILES (N_NODES / 16)            // 6250 exactly

#define BKT_SHIFT 8
#define BKT_NODES 256
#define NBK ((N_NODES + BKT_NODES - 1) / BKT_NODES)      // 391 buckets
#define CHUNK 4096
#define NCHUNKS ((N_EDGES + CHUNK - 1) / CHUNK)          // 391 chunks
#define BSTRIDE 5120                     // fixed bucket capacity (mean 4092 + 16 sigma)

typedef _Float16 half8 __attribute__((ext_vector_type(8)));
typedef float floatx4 __attribute__((ext_vector_type(4)));

// ---------------- pass 1: per-(chunk,bucket) histogram, no global atomics ----------------
__global__ __launch_bounds__(512) void histA_kernel(const int* __restrict__ dst,
                                                    int* __restrict__ hist2d) {
    __shared__ int hist[NBK];
    int t = threadIdx.x;
    int e0 = blockIdx.x * CHUNK;
    int n = N_EDGES - e0; if (n > CHUNK) n = CHUNK;
    for (int i = t; i < NBK; i += 512) hist[i] = 0;
    __syncthreads();
    for (int i = t; i < n; i += 512) atomicAdd(&hist[dst[e0 + i] >> BKT_SHIFT], 1);
    __syncthreads();
    for (int i = t; i < NBK; i += 512) hist2d[blockIdx.x * NBK + i] = hist[i];
}

// ---------------- pass 2: per-bucket scan over chunks -> base2d, btot ----------------
__global__ __launch_bounds__(512) void bscan_kernel(const int* __restrict__ hist2d,
                                                    int* __restrict__ base2d,
                                                    int* __restrict__ btot) {
    __shared__ int ss[512];
    int t = threadIdx.x;
    int b = blockIdx.x;                 // bucket
    int v = (t < NCHUNKS) ? hist2d[t * NBK + b] : 0;
    ss[t] = v;
    __syncthreads();
    for (int off = 1; off < 512; off <<= 1) {
        int u = (t >= off) ? ss[t - off] : 0;
        __syncthreads();
        ss[t] += u;
        __syncthreads();
    }
    if (t < NCHUNKS) base2d[t * NBK + b] = ss[t] - v;   // exclusive within bucket
    if (t == 511) btot[b] = ss[511];
}

// ---------------- pass 3: bin edges into fixed-stride bucket regions (deterministic) ----
// csr_tmp entry packed: (dst & 255) << 24 | src
__global__ __launch_bounds__(512) void binA3_kernel(const int* __restrict__ src,
                                                    const int* __restrict__ dst,
                                                    const int* __restrict__ base2d,
                                                    int* __restrict__ csr_tmp) {
    __shared__ int staged[CHUNK];    // 16 KB
    __shared__ int delta[CHUNK];     // 16 KB
    __shared__ int hist[NBK];
    __shared__ int lcur[NBK];
    __shared__ int gdel[NBK];
    __shared__ int scan_s[512];
    int t = threadIdx.x;
    int e0 = blockIdx.x * CHUNK;
    int n = N_EDGES - e0; if (n > CHUNK) n = CHUNK;

    for (int i = t; i < NBK; i += 512) hist[i] = 0;
    __syncthreads();
    for (int i = t; i < n; i += 512) atomicAdd(&hist[dst[e0 + i] >> BKT_SHIFT], 1);
    __syncthreads();
    int v = (t < NBK) ? hist[t] : 0;
    scan_s[t] = v;
    __syncthreads();
    for (int off = 1; off < 512; off <<= 1) {
        int u = (t >= off) ? scan_s[t - off] : 0;
        __syncthreads();
        scan_s[t] += u;
        __syncthreads();
    }
    if (t < NBK) {
        int excl = scan_s[t] - v;
        lcur[t] = excl;
        // deterministic global run start: bucket base + prefix of earlier chunks
        gdel[t] = t * BSTRIDE + base2d[blockIdx.x * NBK + t] - excl;
    }
    __syncthreads();
    for (int i = t; i < n; i += 512) {
        int s = src[e0 + i];
        int d = dst[e0 + i];
        int bkt = d >> BKT_SHIFT;
        int slot = atomicAdd(&lcur[bkt], 1);
        staged[slot] = ((d & 255) << 24) | s;
        delta[slot] = gdel[bkt];
    }
    __syncthreads();
    for (int p = t; p < n; p += 512) csr_tmp[delta[p] + p] = staged[p];
}

// ---------------- binB2: per-bucket exact CSR + nodeinfo/dinv + fused prescale ----------
__global__ __launch_bounds__(512) void binB2_kernel(const int* __restrict__ btot,
                                                    const int* __restrict__ csr_tmp,
                                                    const float* __restrict__ emb,
                                                    int2* __restrict__ nodeinfo,
                                                    float* __restrict__ dinv,
                                                    int* __restrict__ csr,
                                                    float* __restrict__ Xs) {
    __shared__ int src_s[BSTRIDE];            // 20 KB
    __shared__ unsigned char dloc[BSTRIDE];   // 5 KB
    __shared__ int out_s[BSTRIDE];            // 20 KB
    __shared__ int lcnt[BKT_NODES];
    __shared__ int ss[512];
    __shared__ int lcur[BKT_NODES];
    __shared__ float dinv_s[BKT_NODES];
    int t = threadIdx.x;
    int node0 = blockIdx.x * BKT_NODES;
    int base = blockIdx.x * BSTRIDE;
    int cnt = btot[blockIdx.x];
    if (cnt > BSTRIDE) cnt = BSTRIDE;         // safety (never triggers)
    if (t < BKT_NODES) lcnt[t] = 0;
    __syncthreads();
    for (int i = t; i < cnt; i += 512) {
        int e = csr_tmp[base + i];
        int dl = (unsigned int)e >> 24;
        src_s[i] = e & 0x00FFFFFF;
        dloc[i] = (unsigned char)dl;
        atomicAdd(&lcnt[dl], 1);
    }
    __syncthreads();
    int v = (t < BKT_NODES) ? lcnt[t] : 0;
    ss[t] = v;
    __syncthreads();
    for (int off = 1; off < 512; off <<= 1) {
        int u = (t >= off) ? ss[t - off] : 0;
        __syncthreads();
        ss[t] += u;
        __syncthreads();
    }
    int excl = ss[t] - v;
    int node = node0 + t;
    if (t < BKT_NODES) {
        lcur[t] = excl;
        if (node < N_NODES) {
            float dv = rsqrtf((float)v + 1.0f);
            nodeinfo[node] = make_int2(base + excl, v);
            dinv[node] = dv;
            dinv_s[t] = dv;
        }
    }
    __syncthreads();
    for (int i = t; i < cnt; i += 512) {
        int slot = atomicAdd(&lcur[dloc[i]], 1);
        out_s[slot] = src_s[i];
    }
    __syncthreads();
    for (int i = t; i < cnt; i += 512) csr[base + i] = out_s[i];

    // fused prescale: Xs[node] = emb[node] * dinv[node] for this bucket's nodes
    int nn = N_NODES - node0; if (nn > BKT_NODES) nn = BKT_NODES;
    const float4* E = (const float4*)emb;
    float4* X = (float4*)Xs;
    for (int f = t; f < nn * 16; f += 512) {
        int loc = f >> 4;
        float d = dinv_s[loc];
        float4 val = E[(size_t)(node0 + loc) * 16 + (f & 15)];
        X[(size_t)(node0 + loc) * 16 + (f & 15)] =
            make_float4(val.x * d, val.y * d, val.z * d, val.w * d);
    }
}

// ---------------- pure gather: Agg[n] = dinv[n] * (Xs[n] + sum_{s in in(n)} Xs[s]) --------
// dual-stream edge loop (proven: VGPR 24, occ 77%, ~60 us); nodeinfo = int2(beg, deg)
__global__ __launch_bounds__(256) void gather_kernel(
    const float* __restrict__ Xs, const float* __restrict__ dinv,
    const int2* __restrict__ nodeinfo, const int* __restrict__ csr,
    float* __restrict__ Agg, int n_waves) {
    int lane = threadIdx.x & 63;
    int wid = (blockIdx.x * blockDim.x + threadIdx.x) >> 6;
    int sub = lane >> 4;       // 0..3: edge slot within 4-group
    int l16 = lane & 15;       // 4-channel group
    const float4* Xv = (const float4*)Xs;
    float4* Av = (float4*)Agg;

    for (int node = wid; node < N_NODES; node += n_waves) {
        float di = dinv[node];
        int2 ni = nodeinfo[node];
        int beg = ni.x, end = ni.x + ni.y;
        float4 acc;
        if (sub == 0) {
            acc = Xv[(size_t)node * 16 + l16];   // own (pre-scaled) row
        } else {
            acc = make_float4(0.f, 0.f, 0.f, 0.f);
        }
        int i = beg + sub;                       // stream0: i, i+8, ...  stream1: i+4, i+12, ...
        int sA0 = (i      < end) ? csr[i]      : 0;
        int sA1 = (i + 4  < end) ? csr[i + 4]  : 0;
        int sB0 = (i + 8  < end) ? csr[i + 8]  : 0;
        int sB1 = (i + 12 < end) ? csr[i + 12] : 0;
        float4 rA0 = Xv[(size_t)sA0 * 16 + l16];
        float4 rA1 = Xv[(size_t)sA1 * 16 + l16];
        while (i < end) {
            float4 rB0 = Xv[(size_t)sB0 * 16 + l16];
            float4 rB1 = Xv[(size_t)sB1 * 16 + l16];
            int sC0 = (i + 16 < end) ? csr[i + 16] : 0;
            int sC1 = (i + 20 < end) ? csr[i + 20] : 0;
            float m1 = (i + 4 < end) ? 1.0f : 0.0f;   // stream0 add covered by loop cond
            acc.x += rA0.x; acc.y += rA0.y; acc.z += rA0.z; acc.w += rA0.w;
            acc.x = fmaf(rA1.x, m1, acc.x);
            acc.y = fmaf(rA1.y, m1, acc.y);
            acc.z = fmaf(rA1.z, m1, acc.z);
            acc.w = fmaf(rA1.w, m1, acc.w);
            rA0 = rB0; rA1 = rB1;
            sB0 = sC0; sB1 = sC1;
            i += 8;
        }
        acc.x += __shfl_xor(acc.x, 16, 64); acc.y += __shfl_xor(acc.y, 16, 64);
        acc.z += __shfl_xor(acc.z, 16, 64); acc.w += __shfl_xor(acc.w, 16, 64);
        acc.x += __shfl_xor(acc.x, 32, 64); acc.y += __shfl_xor(acc.y, 32, 64);
        acc.z += __shfl_xor(acc.z, 32, 64); acc.w += __shfl_xor(acc.w, 32, 64);
        if (sub == 0) {
            acc.x *= di; acc.y *= di; acc.z *= di; acc.w *= di;
            Av[(size_t)node * 16 + l16] = acc;
        }
    }
}

// ---------------- MFMA dense epilogue: out = (A @ W + b) [* dinv] ----------------
// f16x2 split precision (proven): hh+hl+lh+ll fp32-accumulated.
// A row = lane&15; B col = lane&15; k = 32c + 8g + j; D: col = lane&15, row = 4g + reg.
__global__ __launch_bounds__(256) void mlp_mfma_kernel(
    const float* __restrict__ A, const float* __restrict__ W,
    const float* __restrict__ b, const float* __restrict__ dinv,
    float* __restrict__ out, int n_waves, int prescale_out) {
    int l = threadIdx.x & 63;
    int wv = threadIdx.x >> 6;
    int m = l & 15;
    int g = l >> 4;
    int wid = blockIdx.x * 4 + wv;

    half8 wh[4][2], wl[4][2];
#pragma unroll
    for (int t = 0; t < 4; t++) {
#pragma unroll
        for (int c = 0; c < 2; c++) {
#pragma unroll
            for (int j = 0; j < 8; j++) {
                float w = W[(32 * c + 8 * g + j) * 64 + 16 * t + m];
                _Float16 h = (_Float16)w;
                wh[t][c][j] = h;
                wl[t][c][j] = (_Float16)(w - (float)h);
            }
        }
    }
    float bfrag[4];
#pragma unroll
    for (int t = 0; t < 4; t++) bfrag[t] = b[16 * t + m];

    const float4* Avv = (const float4*)A;

    for (int tile = wid; tile < NTILES; tile += n_waves) {
        int node0 = tile * 16;
        int row = node0 + m;
        half8 ah[2], al[2];
#pragma unroll
        for (int c = 0; c < 2; c++) {
            float4 a0 = Avv[(size_t)row * 16 + 8 * c + 2 * g];
            float4 a1 = Avv[(size_t)row * 16 + 8 * c + 2 * g + 1];
            float av[8] = {a0.x, a0.y, a0.z, a0.w, a1.x, a1.y, a1.z, a1.w};
#pragma unroll
            for (int j = 0; j < 8; j++) {
                _Float16 h = (_Float16)av[j];
                ah[c][j] = h;
                al[c][j] = (_Float16)(av[j] - (float)h);
            }
        }

        floatx4 acc[4];
#pragma unroll
        for (int t = 0; t < 4; t++) { acc[t][0] = 0.f; acc[t][1] = 0.f; acc[t][2] = 0.f; acc[t][3] = 0.f; }

#pragma unroll
        for (int c = 0; c < 2; c++) {
#pragma unroll
            for (int t = 0; t < 4; t++) {
                acc[t] = __builtin_amdgcn_mfma_f32_16x16x32_f16(ah[c], wh[t][c], acc[t], 0, 0, 0);
                acc[t] = __builtin_amdgcn_mfma_f32_16x16x32_f16(ah[c], wl[t][c], acc[t], 0, 0, 0);
                acc[t] = __builtin_amdgcn_mfma_f32_16x16x32_f16(al[c], wh[t][c], acc[t], 0, 0, 0);
                acc[t] = __builtin_amdgcn_mfma_f32_16x16x32_f16(al[c], wl[t][c], acc[t], 0, 0, 0);
            }
        }

        float dv[4];
#pragma unroll
        for (int r = 0; r < 4; r++) dv[r] = dinv[node0 + 4 * g + r];
#pragma unroll
        for (int t = 0; t < 4; t++) {
#pragma unroll
            for (int r = 0; r < 4; r++) {
                float v = acc[t][r] + bfrag[t];
                if (prescale_out) v *= dv[r];
                out[(size_t)(node0 + 4 * g + r) * 64 + 16 * t + m] = v;
            }
        }
    }
}

extern "C" void kernel_launch(void* const* d_in, const int* in_sizes, int n_in,
                              void* d_out, int out_size, void* d_ws, size_t ws_size,
                              hipStream_t stream) {
    const float* emb = (const float*)d_in[0];
    const int* edge  = (const int*)d_in[1];
    const float* W1 = (const float*)d_in[2];
    const float* b1 = (const float*)d_in[3];
    const float* W2 = (const float*)d_in[4];
    const float* b2 = (const float*)d_in[5];
    const float* W3 = (const float*)d_in[6];
    const float* b3 = (const float*)d_in[7];
    float* out = (float*)d_out;

    const int* src = edge;
    const int* dst = edge + N_EDGES;

    char* ws = (char*)d_ws;
    size_t off = 0;
    int* btot = (int*)(ws + off);        off += 2048;
    int* hist2d = (int*)(ws + off);      off += 612352;   // NCHUNKS*NBK ints
    int* base2d = (int*)(ws + off);      off += 612352;
    int2* nodeinfo = (int2*)(ws + off);  off += 800256;   // N_NODES int2
    float* dinv = (float*)(ws + off);    off += 400128;
    int* csr_tmp = (int*)(ws + off);     off += 8007680;  // NBK*BSTRIDE packed
    int* csr = (int*)(ws + off);         off += 8007680;
    float* Xa = (float*)(ws + off);      off += 25600000;
    float* Xb = (float*)(ws + off);      // 25.6 MB

    // ---- deterministic CSR build (no global atomics, fixed-stride buckets) ----
    histA_kernel<<<NCHUNKS, 512, 0, stream>>>(dst, hist2d);
    bscan_kernel<<<NBK, 512, 0, stream>>>(hist2d, base2d, btot);
    binA3_kernel<<<NCHUNKS, 512, 0, stream>>>(src, dst, base2d, csr_tmp);
    binB2_kernel<<<NBK, 512, 0, stream>>>(btot, csr_tmp, emb, nodeinfo, dinv, csr, Xa);

    const int GBLOCKS = 2048;                 // 8192 waves (full residency)
    const int n_waves = GBLOCKS * 256 / 64;
    const int MBLOCKS = 512;                  // 2048 waves, ~3 tiles/wave
    const int m_waves = MBLOCKS * 256 / 64;

    // layer 1
    gather_kernel<<<GBLOCKS, 256, 0, stream>>>(Xa, dinv, nodeinfo, csr, Xb, n_waves);
    mlp_mfma_kernel<<<MBLOCKS, 256, 0, stream>>>(Xb, W1, b1, dinv, Xa, m_waves, 1);
    // layer 2
    gather_kernel<<<GBLOCKS, 256, 0, stream>>>(Xa, dinv, nodeinfo, csr, Xb, n_waves);
    mlp_mfma_kernel<<<MBLOCKS, 256, 0, stream>>>(Xb, W2, b2, dinv, Xa, m_waves, 1);
    // layer 3 (no prescale on final output)
    gather_kernel<<<GBLOCKS, 256, 0, stream>>>(Xa, dinv, nodeinfo, csr, Xb, n_waves);
    mlp_mfma_kernel<<<MBLOCKS, 256, 0, stream>>>(Xb, W3, b3, dinv, out, m_waves, 0);
}